// Round 5
// baseline (1519.481 us; speedup 1.0000x reference)
//
#include <hip/hip_runtime.h>
#include <math.h>

#define T_STEPS 20

// fast transcendentals: v_exp + v_rcp (~1e-7 abs err; threshold is 9.7e-3)
__device__ __forceinline__ float sigm(float v) {
  return __builtin_amdgcn_rcpf(1.0f + __expf(-v));
}
__device__ __forceinline__ float tanh_f(float v) {
  return 1.0f - 2.0f * __builtin_amdgcn_rcpf(1.0f + __expf(2.0f * v));
}
__device__ __forceinline__ float dot4(float4 a, float4 w, float acc) {
  acc = fmaf(a.x, w.x, acc);
  acc = fmaf(a.y, w.y, acc);
  acc = fmaf(a.z, w.z, acc);
  acc = fmaf(a.w, w.w, acc);
  return acc;
}

// ============================================================================
// SPLIT kernel: 256 blocks × 512 threads; block = (batch b, half) handling 32
// nodes with 16 lanes/node (identical per-node layout to the verified R4
// kernel). Per step, halves exchange their 32×32 a-tile through d_ws (L3)
// with agent-scope atomics + per-half monotonic flags (double-buffered by t
// parity). All 256 blocks are co-resident (capacity >= 768), so the pairwise
// spin cannot deadlock. ZERO per-thread arrays (R1/R2: arrays = scratch).
// ============================================================================
__global__ __launch_bounds__(512)
void traj_disc_split(const float* __restrict__ x, const float* __restrict__ dmat,
                     const float* __restrict__ bmat, const float* __restrict__ hmat,
                     const float* __restrict__ maskp,
                     const float* __restrict__ embW, const float* __restrict__ embb,
                     const float* __restrict__ Wih, const float* __restrict__ Whh,
                     const float* __restrict__ bih, const float* __restrict__ bhh,
                     const float* __restrict__ dom,
                     const float* __restrict__ e2aW, const float* __restrict__ e2ab,
                     const float* __restrict__ spaW, const float* __restrict__ spab,
                     const float* __restrict__ a2eW, const float* __restrict__ a2eb,
                     const float* __restrict__ clsW, const float* __restrict__ clsb,
                     const float* __restrict__ h0p, const float* __restrict__ c0p,
                     unsigned* __restrict__ flags, float* __restrict__ ws_a,
                     float* __restrict__ out)
{
  __shared__ __align__(16) float sg[128*36];   // [Whh(32)|M0,M1,bias'] pitch 36
  __shared__ float sdom[144];
  __shared__ __align__(16) float se2a[32*36];
  __shared__ float se2ab[32];
  __shared__ __align__(16) float sspa[32*68];
  __shared__ float sspab[32];
  __shared__ __align__(16) float sa2e[32*36];
  __shared__ float sa2eb[32];
  __shared__ float sclsW[32];
  __shared__ float sclsb;
  __shared__ float sm[1280];                   // full batch mask [n][t]
  __shared__ __align__(16) float sh[32*36];    // own 32 h rows
  __shared__ __align__(16) float sa[64*72];    // rows 0..31 own a|att (->z); 32..63 partner a
  __shared__ __align__(16) float sw[32*68];    // own normalized edge rows

  const int tid = threadIdx.x;
  const int b    = blockIdx.x >> 1;
  const int half = blockIdx.x & 1;
  const int il = tid >> 4;          // local node 0..31
  const int s  = tid & 15;          // sub-lane 0..15
  const int ig = half*32 + il;      // global node id

  // ---- one-time staging ----
  for (int idx = tid; idx < 4096; idx += 512) sg[(idx >> 5)*36 + (idx & 31)] = Whh[idx];
  if (tid < 128) {
    float m0 = 0.f, m1 = 0.f, bb = bih[tid] + bhh[tid];
    #pragma unroll
    for (int e = 0; e < 16; ++e) {
      float wv_ = Wih[tid*16 + e];
      m0 = fmaf(wv_, embW[2*e],   m0);
      m1 = fmaf(wv_, embW[2*e+1], m1);
      bb = fmaf(wv_, embb[e],     bb);
    }
    sg[tid*36 + 32] = m0; sg[tid*36 + 33] = m1; sg[tid*36 + 34] = bb;
  }
  if (tid < 144) sdom[tid] = dom[tid];
  for (int idx = tid; idx < 1024; idx += 512) se2a[(idx >> 5)*36 + (idx & 31)] = e2aW[idx];
  for (int idx = tid; idx < 2048; idx += 512) sspa[(idx >> 6)*68 + (idx & 63)] = spaW[idx];
  for (int idx = tid; idx < 1024; idx += 512) sa2e[(idx >> 5)*36 + (idx & 31)] = a2eW[idx];
  if (tid < 32) { se2ab[tid] = e2ab[tid]; sspab[tid] = spab[tid]; sa2eb[tid] = a2eb[tid];
                  sclsW[tid] = clsW[tid]; }
  if (tid == 0) sclsb = clsb[0];
  for (int idx = tid; idx < 1280; idx += 512) sm[idx] = maskp[(size_t)b*1280 + idx];
  for (int idx = tid; idx < 1024; idx += 512)
    sh[(idx >> 5)*36 + (idx & 31)] = h0p[(size_t)b*2048 + half*1024 + idx];
  float c0r = c0p[(size_t)b*2048 + half*1024 + il*32 + s];
  float c1r = c0p[(size_t)b*2048 + half*1024 + il*32 + s + 16];
  __syncthreads();

  const size_t nb = (size_t)b*64 + ig;

  #pragma unroll 1
  for (int t = 0; t < T_STEPS; ++t) {
    const size_t ebase = (nb*20 + t)*64;
    const float x0v = x[(nb*20 + t)*2 + 0];
    const float x1v = x[(nb*20 + t)*2 + 1];
#define EDGELD(jj) const float dm##jj = dmat[ebase + s + 16*(jj)]; \
                   const float bm##jj = bmat[ebase + s + 16*(jj)]; \
                   const float hm##jj = hmat[ebase + s + 16*(jj)];
    EDGELD(0) EDGELD(1) EDGELD(2) EDGELD(3)
#undef EDGELD

    // ---- P1: LSTM cell; lane owns hh = s, s+16 ----
    {
      const float4* hrow4 = (const float4*)(sh + il*36);
      const float4 h0_ = hrow4[0], h1_ = hrow4[1], h2_ = hrow4[2], h3_ = hrow4[3];
      const float4 h4_ = hrow4[4], h5_ = hrow4[5], h6_ = hrow4[6], h7_ = hrow4[7];
#define GDOT(q, hh, dst) { const float* r_ = sg + ((q)*32 + (hh))*36; \
      const float4 mb_ = *(const float4*)(r_ + 32); \
      float a_ = fmaf(x0v, mb_.x, fmaf(x1v, mb_.y, mb_.z)); \
      const float4* w_ = (const float4*)r_; \
      a_ = dot4(h0_, w_[0], a_); a_ = dot4(h1_, w_[1], a_); \
      a_ = dot4(h2_, w_[2], a_); a_ = dot4(h3_, w_[3], a_); \
      a_ = dot4(h4_, w_[4], a_); a_ = dot4(h5_, w_[5], a_); \
      a_ = dot4(h6_, w_[6], a_); a_ = dot4(h7_, w_[7], a_); \
      dst = a_; }
#define LSTM_U(u, creg) { const int hh_ = s + 16*(u); \
      float ai_, af_, ag_, ao_; \
      GDOT(0, hh_, ai_) GDOT(1, hh_, af_) GDOT(2, hh_, ag_) GDOT(3, hh_, ao_) \
      const float ig_ = sigm(ai_), fg_ = sigm(af_), gg_ = tanh_f(ag_), og_ = sigm(ao_); \
      creg = fmaf(fg_, creg, ig_*gg_); \
      sh[il*36 + hh_] = og_ * tanh_f(creg); }
      LSTM_U(0, c0r) LSTM_U(1, c1r)
#undef LSTM_U
#undef GDOT
    }

    // ---- P2: a = h @ enc2att_W^T + b; keep in regs, write LDS + publish ----
    float a0v, a1v;
    {
      const float4* hrow4 = (const float4*)(sh + il*36);
      const float4 g0_ = hrow4[0], g1_ = hrow4[1], g2_ = hrow4[2], g3_ = hrow4[3];
      const float4 g4_ = hrow4[4], g5_ = hrow4[5], g6_ = hrow4[6], g7_ = hrow4[7];
#define AOUT(u, dst) { const int k_ = s + 16*(u); \
      float acc_ = se2ab[k_]; \
      const float4* wr_ = (const float4*)(se2a + k_*36); \
      acc_ = dot4(g0_, wr_[0], acc_); acc_ = dot4(g1_, wr_[1], acc_); \
      acc_ = dot4(g2_, wr_[2], acc_); acc_ = dot4(g3_, wr_[3], acc_); \
      acc_ = dot4(g4_, wr_[4], acc_); acc_ = dot4(g5_, wr_[5], acc_); \
      acc_ = dot4(g6_, wr_[6], acc_); acc_ = dot4(g7_, wr_[7], acc_); \
      dst = acc_; sa[il*72 + k_] = acc_; }
      AOUT(0, a0v) AOUT(1, a1v)
#undef AOUT
    }

    // ---- exchange: publish own a-tile, wait partner, stage partner tile ----
    {
      const int pairbase = ((t & 1) * 128 + b) * 2;
      float* aout = ws_a + (size_t)(pairbase + half) * 1024;
      __hip_atomic_store(&aout[il*32 + s],      a0v, __ATOMIC_RELAXED, __HIP_MEMORY_SCOPE_AGENT);
      __hip_atomic_store(&aout[il*32 + s + 16], a1v, __ATOMIC_RELAXED, __HIP_MEMORY_SCOPE_AGENT);
      __threadfence();   // drain own stores to device coherence point
      __syncthreads();   // S1: all threads' stores drained; own sa rows ready
      if (tid == 0) {
        __hip_atomic_store(&flags[b*2 + half], (unsigned)(t + 1),
                           __ATOMIC_RELEASE, __HIP_MEMORY_SCOPE_AGENT);
        while (__hip_atomic_load(&flags[b*2 + (1 - half)],
                                 __ATOMIC_ACQUIRE, __HIP_MEMORY_SCOPE_AGENT)
               < (unsigned)(t + 1)) {
          __builtin_amdgcn_s_sleep(2);
        }
      }
      __syncthreads();   // S2: partner data visible
      const float* ain = ws_a + (size_t)(pairbase + (1 - half)) * 1024;
      float v0 = __hip_atomic_load(&ain[tid],       __ATOMIC_RELAXED, __HIP_MEMORY_SCOPE_AGENT);
      float v1 = __hip_atomic_load(&ain[tid + 512], __ATOMIC_RELAXED, __HIP_MEMORY_SCOPE_AGENT);
      sa[(32 + (tid >> 5))*72 + (tid & 31)] = v0;
      sa[(48 + (tid >> 5))*72 + (tid & 31)] = v1;
      __syncthreads();   // S3: partner rows 32..63 staged in LDS
    }

    // ---- 3a: normalized edge weights -> sw[il][j], j = 0..63 ----
    {
      const float mi_ = sm[ig*20 + t];
      float rs = 0.0f;
#define WCOMP(jj) float wn##jj; { \
      int ib_ = (int)floorf(bm##jj * (1.0f/30.0f)); ib_ = ib_ < 0 ? 0 : (ib_ > 11 ? 11 : ib_); \
      int ih_ = (int)floorf(hm##jj * (1.0f/30.0f)); ih_ = ih_ < 0 ? 0 : (ih_ > 11 ? 11 : ih_); \
      float w_ = fmaxf(sdom[ib_*12 + ih_] - dm##jj, 0.0f) * (mi_ * sm[(s + 16*(jj))*20 + t]); \
      wn##jj = (s + 16*(jj) == ig) ? 0.0f : w_; rs += wn##jj; }
      WCOMP(0) WCOMP(1) WCOMP(2) WCOMP(3)
#undef WCOMP
      rs += __shfl_xor(rs, 1); rs += __shfl_xor(rs, 2);
      rs += __shfl_xor(rs, 4); rs += __shfl_xor(rs, 8);
      const float inv_ = __builtin_amdgcn_rcpf(rs + 1e-12f);
      sw[il*68 + s +  0] = wn0 * inv_;
      sw[il*68 + s + 16] = wn1 * inv_;
      sw[il*68 + s + 32] = wn2 * inv_;
      sw[il*68 + s + 48] = wn3 * inv_;
    }

    // ---- 3b: att[il][m]; lane (p = s>>3) sums its j-half for m4 = s&7 ----
    {
      const int p  = s >> 3;
      const int m8 = s & 7;
      const float* wrow = sw + il*68 + 32*p;
      const float4 w0_ = *(const float4*)(wrow +  0);
      const float4 w1_ = *(const float4*)(wrow +  4);
      const float4 w2_ = *(const float4*)(wrow +  8);
      const float4 w3_ = *(const float4*)(wrow + 12);
      const float4 w4_ = *(const float4*)(wrow + 16);
      const float4 w5_ = *(const float4*)(wrow + 20);
      const float4 w6_ = *(const float4*)(wrow + 24);
      const float4 w7_ = *(const float4*)(wrow + 28);
      float ax = 0.f, ay = 0.f, az = 0.f, aw = 0.f;
      const float* abase = sa + 4*m8 + (size_t)(32*p)*72;
#define AJ(c, r, wv) { const float4 av_ = *(const float4*)(abase + (4*(c) + (r))*72); \
      ax = fmaf(wv, av_.x, ax); ay = fmaf(wv, av_.y, ay); \
      az = fmaf(wv, av_.z, az); aw = fmaf(wv, av_.w, aw); }
#define AJ4(c, wreg) AJ(c, 0, wreg.x) AJ(c, 1, wreg.y) AJ(c, 2, wreg.z) AJ(c, 3, wreg.w)
      AJ4(0, w0_) AJ4(1, w1_) AJ4(2, w2_) AJ4(3, w3_)
      AJ4(4, w4_) AJ4(5, w5_) AJ4(6, w6_) AJ4(7, w7_)
#undef AJ4
#undef AJ
      ax += __shfl_xor(ax, 8); ay += __shfl_xor(ay, 8);
      az += __shfl_xor(az, 8); aw += __shfl_xor(aw, 8);
      if (p == 0) {
        float* d = sa + il*72 + 36 + 4*m8;
        d[0] = ax; d[1] = ay; d[2] = az; d[3] = aw;
      }
    }
    // att written by own node's lanes (same wave) -> P4 needs no barrier

    // ---- P4: z_k = tanh([a|att][il] . spa_W[k] + b), k = s+16u ----
    float zv0, zv1;
    {
      const float4* arow4 = (const float4*)(sa + il*72);
      const float4 a0_ = arow4[0], a1_ = arow4[1], a2_ = arow4[2], a3_ = arow4[3];
      const float4 a4_ = arow4[4], a5_ = arow4[5], a6_ = arow4[6], a7_ = arow4[7];
      const float4* trow4 = (const float4*)(sa + il*72 + 36);
      const float4 t0_ = trow4[0], t1_ = trow4[1], t2_ = trow4[2], t3_ = trow4[3];
      const float4 t4_ = trow4[4], t5_ = trow4[5], t6_ = trow4[6], t7_ = trow4[7];
#define ZCOMP(u, zdst) { const int k_ = s + 16*(u); \
      float acc_ = sspab[k_]; \
      const float4* wr_ = (const float4*)(sspa + k_*68); \
      acc_ = dot4(a0_, wr_[0], acc_); acc_ = dot4(a1_, wr_[1], acc_); \
      acc_ = dot4(a2_, wr_[2], acc_); acc_ = dot4(a3_, wr_[3], acc_); \
      acc_ = dot4(a4_, wr_[4], acc_); acc_ = dot4(a5_, wr_[5], acc_); \
      acc_ = dot4(a6_, wr_[6], acc_); acc_ = dot4(a7_, wr_[7], acc_); \
      acc_ = dot4(t0_, wr_[8],  acc_); acc_ = dot4(t1_, wr_[9],  acc_); \
      acc_ = dot4(t2_, wr_[10], acc_); acc_ = dot4(t3_, wr_[11], acc_); \
      acc_ = dot4(t4_, wr_[12], acc_); acc_ = dot4(t5_, wr_[13], acc_); \
      acc_ = dot4(t6_, wr_[14], acc_); acc_ = dot4(t7_, wr_[15], acc_); \
      zdst = tanh_f(acc_); }
      ZCOMP(0, zv0) ZCOMP(1, zv1)
#undef ZCOMP
    }
    __syncthreads();   // S4: cross-wave reads of own a rows done -> reuse for z
    sa[il*72 + s]      = zv0;
    sa[il*72 + s + 16] = zv1;

    // ---- P5: h = z @ att2enc_W^T + b (row-local, same-wave) ----
    {
      const float4* zrow4 = (const float4*)(sa + il*72);
      const float4 z0_ = zrow4[0], z1_ = zrow4[1], z2_ = zrow4[2], z3_ = zrow4[3];
      const float4 z4_ = zrow4[4], z5_ = zrow4[5], z6_ = zrow4[6], z7_ = zrow4[7];
#define HOUT(u) { const int k_ = s + 16*(u); \
      float acc_ = sa2eb[k_]; \
      const float4* wr_ = (const float4*)(sa2e + k_*36); \
      acc_ = dot4(z0_, wr_[0], acc_); acc_ = dot4(z1_, wr_[1], acc_); \
      acc_ = dot4(z2_, wr_[2], acc_); acc_ = dot4(z3_, wr_[3], acc_); \
      acc_ = dot4(z4_, wr_[4], acc_); acc_ = dot4(z5_, wr_[5], acc_); \
      acc_ = dot4(z6_, wr_[6], acc_); acc_ = dot4(z7_, wr_[7], acc_); \
      sh[il*36 + k_] = acc_; }
      HOUT(0) HOUT(1)
#undef HOUT
    }
  }
  __syncthreads();

  // ---- classifier head ----
  if (tid < 32) {
    float acc = sclsb;
    #pragma unroll
    for (int hh = 0; hh < 32; ++hh) acc = fmaf(sh[tid*36 + hh], sclsW[hh], acc);
    out[(size_t)b*64 + half*32 + tid] = sigm(tanh_f(acc));
  }
}

// ============================================================================
// Fallback: R4 monolithic kernel (128 blocks × 1024 thr), used if ws_size is
// too small for the exchange buffers. Verified absmax=0.0 at 222 µs.
// ============================================================================
__global__ __launch_bounds__(1024)
void traj_disc_mono(const float* __restrict__ x, const float* __restrict__ dmat,
                    const float* __restrict__ bmat, const float* __restrict__ hmat,
                    const float* __restrict__ maskp,
                    const float* __restrict__ embW, const float* __restrict__ embb,
                    const float* __restrict__ Wih, const float* __restrict__ Whh,
                    const float* __restrict__ bih, const float* __restrict__ bhh,
                    const float* __restrict__ dom,
                    const float* __restrict__ e2aW, const float* __restrict__ e2ab,
                    const float* __restrict__ spaW, const float* __restrict__ spab,
                    const float* __restrict__ a2eW, const float* __restrict__ a2eb,
                    const float* __restrict__ clsW, const float* __restrict__ clsb,
                    const float* __restrict__ h0p, const float* __restrict__ c0p,
                    float* __restrict__ out)
{
  __shared__ __align__(16) float sg[128*36];
  __shared__ float sdom[144];
  __shared__ __align__(16) float se2a[32*36];
  __shared__ float se2ab[32];
  __shared__ __align__(16) float sspa[32*68];
  __shared__ float sspab[32];
  __shared__ __align__(16) float sa2e[32*36];
  __shared__ float sa2eb[32];
  __shared__ float sclsW[32];
  __shared__ float sclsb;
  __shared__ float sm[1280];
  __shared__ __align__(16) float sh[64*36];
  __shared__ __align__(16) float sa[64*72];
  __shared__ __align__(16) float sw[64*68];

  const int tid = threadIdx.x;
  const int b = blockIdx.x;
  const int i = tid >> 4;
  const int s = tid & 15;

  for (int idx = tid; idx < 4096; idx += 1024) sg[(idx >> 5)*36 + (idx & 31)] = Whh[idx];
  if (tid < 128) {
    float m0 = 0.f, m1 = 0.f, bb = bih[tid] + bhh[tid];
    #pragma unroll
    for (int e = 0; e < 16; ++e) {
      float wv_ = Wih[tid*16 + e];
      m0 = fmaf(wv_, embW[2*e],   m0);
      m1 = fmaf(wv_, embW[2*e+1], m1);
      bb = fmaf(wv_, embb[e],     bb);
    }
    sg[tid*36 + 32] = m0; sg[tid*36 + 33] = m1; sg[tid*36 + 34] = bb;
  }
  if (tid < 144) sdom[tid] = dom[tid];
  for (int idx = tid; idx < 1024; idx += 1024) se2a[(idx >> 5)*36 + (idx & 31)] = e2aW[idx];
  for (int idx = tid; idx < 2048; idx += 1024) sspa[(idx >> 6)*68 + (idx & 63)] = spaW[idx];
  for (int idx = tid; idx < 1024; idx += 1024) sa2e[(idx >> 5)*36 + (idx & 31)] = a2eW[idx];
  if (tid < 32) { se2ab[tid] = e2ab[tid]; sspab[tid] = spab[tid]; sa2eb[tid] = a2eb[tid];
                  sclsW[tid] = clsW[tid]; }
  if (tid == 0) sclsb = clsb[0];
  for (int idx = tid; idx < 1280; idx += 1024) sm[idx] = maskp[(size_t)b*1280 + idx];
  for (int idx = tid; idx < 2048; idx += 1024) sh[(idx >> 5)*36 + (idx & 31)] = h0p[(size_t)b*2048 + idx];
  float c0r = c0p[(size_t)b*2048 + i*32 + s];
  float c1r = c0p[(size_t)b*2048 + i*32 + s + 16];
  __syncthreads();

  const size_t nb = (size_t)b*64 + i;

  #pragma unroll 1
  for (int t = 0; t < T_STEPS; ++t) {
    const size_t ebase = (nb*20 + t)*64;
    const float x0v = x[(nb*20 + t)*2 + 0];
    const float x1v = x[(nb*20 + t)*2 + 1];
#define EDGELD(jj) const float dm##jj = dmat[ebase + s + 16*(jj)]; \
                   const float bm##jj = bmat[ebase + s + 16*(jj)]; \
                   const float hm##jj = hmat[ebase + s + 16*(jj)];
    EDGELD(0) EDGELD(1) EDGELD(2) EDGELD(3)
#undef EDGELD
    {
      const float4* hrow4 = (const float4*)(sh + i*36);
      const float4 h0_ = hrow4[0], h1_ = hrow4[1], h2_ = hrow4[2], h3_ = hrow4[3];
      const float4 h4_ = hrow4[4], h5_ = hrow4[5], h6_ = hrow4[6], h7_ = hrow4[7];
#define GDOT(q, hh, dst) { const float* r_ = sg + ((q)*32 + (hh))*36; \
      const float4 mb_ = *(const float4*)(r_ + 32); \
      float a_ = fmaf(x0v, mb_.x, fmaf(x1v, mb_.y, mb_.z)); \
      const float4* w_ = (const float4*)r_; \
      a_ = dot4(h0_, w_[0], a_); a_ = dot4(h1_, w_[1], a_); \
      a_ = dot4(h2_, w_[2], a_); a_ = dot4(h3_, w_[3], a_); \
      a_ = dot4(h4_, w_[4], a_); a_ = dot4(h5_, w_[5], a_); \
      a_ = dot4(h6_, w_[6], a_); a_ = dot4(h7_, w_[7], a_); \
      dst = a_; }
#define LSTM_U(u, creg) { const int hh_ = s + 16*(u); \
      float ai_, af_, ag_, ao_; \
      GDOT(0, hh_, ai_) GDOT(1, hh_, af_) GDOT(2, hh_, ag_) GDOT(3, hh_, ao_) \
      const float ig_ = sigm(ai_), fg_ = sigm(af_), gg_ = tanh_f(ag_), og_ = sigm(ao_); \
      creg = fmaf(fg_, creg, ig_*gg_); \
      sh[i*36 + hh_] = og_ * tanh_f(creg); }
      LSTM_U(0, c0r) LSTM_U(1, c1r)
#undef LSTM_U
#undef GDOT
    }
    {
      const float4* hrow4 = (const float4*)(sh + i*36);
      const float4 g0_ = hrow4[0], g1_ = hrow4[1], g2_ = hrow4[2], g3_ = hrow4[3];
      const float4 g4_ = hrow4[4], g5_ = hrow4[5], g6_ = hrow4[6], g7_ = hrow4[7];
#define AOUT(u) { const int k_ = s + 16*(u); \
      float acc_ = se2ab[k_]; \
      const float4* wr_ = (const float4*)(se2a + k_*36); \
      acc_ = dot4(g0_, wr_[0], acc_); acc_ = dot4(g1_, wr_[1], acc_); \
      acc_ = dot4(g2_, wr_[2], acc_); acc_ = dot4(g3_, wr_[3], acc_); \
      acc_ = dot4(g4_, wr_[4], acc_); acc_ = dot4(g5_, wr_[5], acc_); \
      acc_ = dot4(g6_, wr_[6], acc_); acc_ = dot4(g7_, wr_[7], acc_); \
      sa[i*72 + k_] = acc_; }
      AOUT(0) AOUT(1)
#undef AOUT
    }
    __syncthreads();
    {
      const float mi_ = sm[i*20 + t];
      float rs = 0.0f;
#define WCOMP(jj) float wn##jj; { \
      int ib_ = (int)floorf(bm##jj * (1.0f/30.0f)); ib_ = ib_ < 0 ? 0 : (ib_ > 11 ? 11 : ib_); \
      int ih_ = (int)floorf(hm##jj * (1.0f/30.0f)); ih_ = ih_ < 0 ? 0 : (ih_ > 11 ? 11 : ih_); \
      float w_ = fmaxf(sdom[ib_*12 + ih_] - dm##jj, 0.0f) * (mi_ * sm[(s + 16*(jj))*20 + t]); \
      wn##jj = (s + 16*(jj) == i) ? 0.0f : w_; rs += wn##jj; }
      WCOMP(0) WCOMP(1) WCOMP(2) WCOMP(3)
#undef WCOMP
      rs += __shfl_xor(rs, 1); rs += __shfl_xor(rs, 2);
      rs += __shfl_xor(rs, 4); rs += __shfl_xor(rs, 8);
      const float inv_ = __builtin_amdgcn_rcpf(rs + 1e-12f);
      sw[i*68 + s +  0] = wn0 * inv_;
      sw[i*68 + s + 16] = wn1 * inv_;
      sw[i*68 + s + 32] = wn2 * inv_;
      sw[i*68 + s + 48] = wn3 * inv_;
    }
    {
      const int p  = s >> 3;
      const int m8 = s & 7;
      const float* wrow = sw + i*68 + 32*p;
      const float4 w0_ = *(const float4*)(wrow +  0);
      const float4 w1_ = *(const float4*)(wrow +  4);
      const float4 w2_ = *(const float4*)(wrow +  8);
      const float4 w3_ = *(const float4*)(wrow + 12);
      const float4 w4_ = *(const float4*)(wrow + 16);
      const float4 w5_ = *(const float4*)(wrow + 20);
      const float4 w6_ = *(const float4*)(wrow + 24);
      const float4 w7_ = *(const float4*)(wrow + 28);
      float ax = 0.f, ay = 0.f, az = 0.f, aw = 0.f;
      const float* abase = sa + 4*m8 + (size_t)(32*p)*72;
#define AJ(c, r, wv) { const float4 av_ = *(const float4*)(abase + (4*(c) + (r))*72); \
      ax = fmaf(wv, av_.x, ax); ay = fmaf(wv, av_.y, ay); \
      az = fmaf(wv, av_.z, az); aw = fmaf(wv, av_.w, aw); }
#define AJ4(c, wreg) AJ(c, 0, wreg.x) AJ(c, 1, wreg.y) AJ(c, 2, wreg.z) AJ(c, 3, wreg.w)
      AJ4(0, w0_) AJ4(1, w1_) AJ4(2, w2_) AJ4(3, w3_)
      AJ4(4, w4_) AJ4(5, w5_) AJ4(6, w6_) AJ4(7, w7_)
#undef AJ4
#undef AJ
      ax += __shfl_xor(ax, 8); ay += __shfl_xor(ay, 8);
      az += __shfl_xor(az, 8); aw += __shfl_xor(aw, 8);
      if (p == 0) {
        float* d = sa + i*72 + 36 + 4*m8;
        d[0] = ax; d[1] = ay; d[2] = az; d[3] = aw;
      }
    }
    float zv0, zv1;
    {
      const float4* arow4 = (const float4*)(sa + i*72);
      const float4 a0_ = arow4[0], a1_ = arow4[1], a2_ = arow4[2], a3_ = arow4[3];
      const float4 a4_ = arow4[4], a5_ = arow4[5], a6_ = arow4[6], a7_ = arow4[7];
      const float4* trow4 = (const float4*)(sa + i*72 + 36);
      const float4 t0_ = trow4[0], t1_ = trow4[1], t2_ = trow4[2], t3_ = trow4[3];
      const float4 t4_ = trow4[4], t5_ = trow4[5], t6_ = trow4[6], t7_ = trow4[7];
#define ZCOMP(u, zdst) { const int k_ = s + 16*(u); \
      float acc_ = sspab[k_]; \
      const float4* wr_ = (const float4*)(sspa + k_*68); \
      acc_ = dot4(a0_, wr_[0], acc_); acc_ = dot4(a1_, wr_[1], acc_); \
      acc_ = dot4(a2_, wr_[2], acc_); acc_ = dot4(a3_, wr_[3], acc_); \
      acc_ = dot4(a4_, wr_[4], acc_); acc_ = dot4(a5_, wr_[5], acc_); \
      acc_ = dot4(a6_, wr_[6], acc_); acc_ = dot4(a7_, wr_[7], acc_); \
      acc_ = dot4(t0_, wr_[8],  acc_); acc_ = dot4(t1_, wr_[9],  acc_); \
      acc_ = dot4(t2_, wr_[10], acc_); acc_ = dot4(t3_, wr_[11], acc_); \
      acc_ = dot4(t4_, wr_[12], acc_); acc_ = dot4(t5_, wr_[13], acc_); \
      acc_ = dot4(t6_, wr_[14], acc_); acc_ = dot4(t7_, wr_[15], acc_); \
      zdst = tanh_f(acc_); }
      ZCOMP(0, zv0) ZCOMP(1, zv1)
#undef ZCOMP
    }
    __syncthreads();
    sa[i*72 + s]      = zv0;
    sa[i*72 + s + 16] = zv1;
    {
      const float4* zrow4 = (const float4*)(sa + i*72);
      const float4 z0_ = zrow4[0], z1_ = zrow4[1], z2_ = zrow4[2], z3_ = zrow4[3];
      const float4 z4_ = zrow4[4], z5_ = zrow4[5], z6_ = zrow4[6], z7_ = zrow4[7];
#define HOUT(u) { const int k_ = s + 16*(u); \
      float acc_ = sa2eb[k_]; \
      const float4* wr_ = (const float4*)(sa2e + k_*36); \
      acc_ = dot4(z0_, wr_[0], acc_); acc_ = dot4(z1_, wr_[1], acc_); \
      acc_ = dot4(z2_, wr_[2], acc_); acc_ = dot4(z3_, wr_[3], acc_); \
      acc_ = dot4(z4_, wr_[4], acc_); acc_ = dot4(z5_, wr_[5], acc_); \
      acc_ = dot4(z6_, wr_[6], acc_); acc_ = dot4(z7_, wr_[7], acc_); \
      sh[i*36 + k_] = acc_; }
      HOUT(0) HOUT(1)
#undef HOUT
    }
  }
  __syncthreads();
  if (tid < 64) {
    float acc = sclsb;
    #pragma unroll
    for (int hh = 0; hh < 32; ++hh) acc = fmaf(sh[tid*36 + hh], sclsW[hh], acc);
    out[(size_t)b*64 + tid] = sigm(tanh_f(acc));
  }
}

extern "C" void kernel_launch(void* const* d_in, const int* in_sizes, int n_in,
                              void* d_out, int out_size, void* d_ws, size_t ws_size,
                              hipStream_t stream) {
  (void)in_sizes; (void)n_in; (void)out_size;
  const float* x    = (const float*)d_in[0];
  const float* dmat = (const float*)d_in[1];
  const float* bmat = (const float*)d_in[2];
  const float* hmat = (const float*)d_in[3];
  const float* mask = (const float*)d_in[4];
  const float* embW = (const float*)d_in[5];
  const float* embb = (const float*)d_in[6];
  const float* Wih  = (const float*)d_in[7];
  const float* Whh  = (const float*)d_in[8];
  const float* bih  = (const float*)d_in[9];
  const float* bhh  = (const float*)d_in[10];
  const float* dom  = (const float*)d_in[11];
  const float* e2aW = (const float*)d_in[12];
  const float* e2ab = (const float*)d_in[13];
  const float* spaW = (const float*)d_in[14];
  const float* spab = (const float*)d_in[15];
  const float* a2eW = (const float*)d_in[16];
  const float* a2eb = (const float*)d_in[17];
  const float* clsW = (const float*)d_in[18];
  const float* clsb = (const float*)d_in[19];
  const float* h0   = (const float*)d_in[20];
  const float* c0   = (const float*)d_in[21];
  float* out = (float*)d_out;

  // ws layout: [0,1KB) flags (256 × u32, reset each call); [4KB, 4KB+2MB) a-exchange
  const size_t WS_NEED = 4096 + (size_t)2 * 128 * 2 * 1024 * sizeof(float);
  if (ws_size >= WS_NEED) {
    hipMemsetAsync(d_ws, 0, 1024, stream);
    unsigned* flags = (unsigned*)d_ws;
    float* ws_a = (float*)((char*)d_ws + 4096);
    traj_disc_split<<<dim3(256), dim3(512), 0, stream>>>(
        x, dmat, bmat, hmat, mask, embW, embb, Wih, Whh, bih, bhh, dom,
        e2aW, e2ab, spaW, spab, a2eW, a2eb, clsW, clsb, h0, c0,
        flags, ws_a, out);
  } else {
    traj_disc_mono<<<dim3(128), dim3(1024), 0, stream>>>(
        x, dmat, bmat, hmat, mask, embW, embb, Wih, Whh, bih, bhh, dom,
        e2aW, e2ab, spaW, spab, a2eW, a2eb, clsW, clsb, h0, c0, out);
  }
}

// Round 6
// 274.945 us; speedup vs baseline: 5.5265x; 5.5265x over previous
//
#include <hip/hip_runtime.h>
#include <math.h>

#define T_STEPS 20

typedef _Float16 h2v __attribute__((ext_vector_type(2)));

// fast transcendentals: v_exp + v_rcp (~1e-7 abs err; threshold is 9.7e-3)
__device__ __forceinline__ float sigm(float v) {
  return __builtin_amdgcn_rcpf(1.0f + __expf(-v));
}
__device__ __forceinline__ float tanh_f(float v) {
  return 1.0f - 2.0f * __builtin_amdgcn_rcpf(1.0f + __expf(2.0f * v));
}
// v_dot2_f32_f16: dwords holding 2 packed halves each; f32 accumulate
__device__ __forceinline__ float fdot2(float w, float h, float acc) {
  return __builtin_amdgcn_fdot2(__builtin_bit_cast(h2v, w),
                                __builtin_bit_cast(h2v, h), acc, false);
}
// 32-element f16 dot: 4 float4 of packed halves each side, 16 v_dot2
#define DOT32(acc, W0, W1, W2, W3, H0, H1, H2, H3) \
  acc = fdot2(W0.x, H0.x, acc); acc = fdot2(W0.y, H0.y, acc); \
  acc = fdot2(W0.z, H0.z, acc); acc = fdot2(W0.w, H0.w, acc); \
  acc = fdot2(W1.x, H1.x, acc); acc = fdot2(W1.y, H1.y, acc); \
  acc = fdot2(W1.z, H1.z, acc); acc = fdot2(W1.w, H1.w, acc); \
  acc = fdot2(W2.x, H2.x, acc); acc = fdot2(W2.y, H2.y, acc); \
  acc = fdot2(W2.z, H2.z, acc); acc = fdot2(W2.w, H2.w, acc); \
  acc = fdot2(W3.x, H3.x, acc); acc = fdot2(W3.y, H3.y, acc); \
  acc = fdot2(W3.z, H3.z, acc); acc = fdot2(W3.w, H3.w, acc);

// One block per batch (grid=128, the only shape that works: R5 showed per-step
// cross-block sync costs ~60 µs/step through L3). 1024 threads: node i =
// tid>>4, sub-lane s = tid&15; a node's 16 lanes live in ONE wave. R3/R4
// analysis: the kernel is LDS-pipe-bound (~216 ds_read_b128/wave-step). This
// version stores weights AND activations as f16 and contracts with
// v_dot2_f32_f16 (f32 accumulate): ~112 b128/wave-step, half the fma count.
// ZERO per-thread arrays (R1/R2: arrays = scratch = HBM). 2 barriers/step.
__global__ __launch_bounds__(1024)
void traj_disc(const float* __restrict__ x, const float* __restrict__ dmat,
               const float* __restrict__ bmat, const float* __restrict__ hmat,
               const float* __restrict__ maskp,
               const float* __restrict__ embW, const float* __restrict__ embb,
               const float* __restrict__ Wih, const float* __restrict__ Whh,
               const float* __restrict__ bih, const float* __restrict__ bhh,
               const float* __restrict__ dom,
               const float* __restrict__ e2aW, const float* __restrict__ e2ab,
               const float* __restrict__ spaW, const float* __restrict__ spab,
               const float* __restrict__ a2eW, const float* __restrict__ a2eb,
               const float* __restrict__ clsW, const float* __restrict__ clsb,
               const float* __restrict__ h0p, const float* __restrict__ c0p,
               float* __restrict__ out)
{
  // f16 rows, pitches in halves: 40 (=80B) and 72 (=144B) — 16B-aligned rows,
  // weight-row bank bases 2-way only (free per m136).
  __shared__ __align__(16) _Float16 sgw[128*40];   // Whh gate rows
  __shared__ __align__(16) float4   sgmb[128];     // (M0, M1, bias', 0) f32
  __shared__ float sdom[144];
  __shared__ __align__(16) _Float16 se2a[32*40];
  __shared__ float se2ab[32];
  __shared__ __align__(16) _Float16 sspa[32*72];   // 64 used per row
  __shared__ float sspab[32];
  __shared__ __align__(16) _Float16 sa2e[32*40];
  __shared__ float sa2eb[32];
  __shared__ float sclsW[32];
  __shared__ float sclsb;
  __shared__ float sm[1280];                        // mask[b] as [n][t]
  __shared__ __align__(16) _Float16 sh[64*40];      // h rows f16
  __shared__ __align__(16) _Float16 sazf[64*72];    // [a(32)|att(32)] f16; a part reused for z
  __shared__ __align__(16) _Float16 saT[32*72];     // aT[m][j] f16 (for 3b j-contraction)
  __shared__ __align__(16) _Float16 swf[64*72];     // normalized w[i][j] f16

  const int tid = threadIdx.x;
  const int b = blockIdx.x;
  const int i = tid >> 4;   // node 0..63
  const int s = tid & 15;   // sub-lane 0..15

  // ---- one-time staging (f32 -> f16 for all matmul operands) ----
  for (int idx = tid; idx < 4096; idx += 1024) sgw[(idx >> 5)*40 + (idx & 31)] = (_Float16)Whh[idx];
  if (tid < 128) {
    float m0 = 0.f, m1 = 0.f, bb = bih[tid] + bhh[tid];
    #pragma unroll
    for (int e = 0; e < 16; ++e) {
      float wv_ = Wih[tid*16 + e];
      m0 = fmaf(wv_, embW[2*e],   m0);
      m1 = fmaf(wv_, embW[2*e+1], m1);
      bb = fmaf(wv_, embb[e],     bb);
    }
    sgmb[tid] = make_float4(m0, m1, bb, 0.f);
  }
  if (tid < 144) sdom[tid] = dom[tid];
  for (int idx = tid; idx < 1024; idx += 1024) se2a[(idx >> 5)*40 + (idx & 31)] = (_Float16)e2aW[idx];
  for (int idx = tid; idx < 2048; idx += 1024) sspa[(idx >> 6)*72 + (idx & 63)] = (_Float16)spaW[idx];
  for (int idx = tid; idx < 1024; idx += 1024) sa2e[(idx >> 5)*40 + (idx & 31)] = (_Float16)a2eW[idx];
  if (tid < 32) { se2ab[tid] = e2ab[tid]; sspab[tid] = spab[tid]; sa2eb[tid] = a2eb[tid];
                  sclsW[tid] = clsW[tid]; }
  if (tid == 0) sclsb = clsb[0];
  for (int idx = tid; idx < 1280; idx += 1024) sm[idx] = maskp[(size_t)b*1280 + idx];
  for (int idx = tid; idx < 2048; idx += 1024) sh[(idx >> 5)*40 + (idx & 31)] = (_Float16)h0p[(size_t)b*2048 + idx];
  float c0r = c0p[(size_t)b*2048 + i*32 + s];       // cell state f32, hh = s
  float c1r = c0p[(size_t)b*2048 + i*32 + s + 16];  // cell state f32, hh = s+16
  __syncthreads();

  const size_t nb = (size_t)b*64 + i;

  #pragma unroll 1
  for (int t = 0; t < T_STEPS; ++t) {
    const size_t ebase = (nb*20 + t)*64;
    const float x0v = x[(nb*20 + t)*2 + 0];
    const float x1v = x[(nb*20 + t)*2 + 1];
    // 12 NAMED edge scalars (never an array)
#define EDGELD(jj) const float dm##jj = dmat[ebase + s + 16*(jj)]; \
                   const float bm##jj = bmat[ebase + s + 16*(jj)]; \
                   const float hm##jj = hmat[ebase + s + 16*(jj)];
    EDGELD(0) EDGELD(1) EDGELD(2) EDGELD(3)
#undef EDGELD

    // ---- P1: LSTM cell; lane owns hh = s, s+16 ----
    {
      const float4* hp = (const float4*)(sh + i*40);   // h_{t-1} as 16 h2 pairs
      const float4 HA = hp[0], HB = hp[1], HC = hp[2], HD = hp[3];
#define GDOTF(q, hh, dst) { \
      const float4 mb_ = sgmb[(q)*32 + (hh)]; \
      float a_ = fmaf(x0v, mb_.x, fmaf(x1v, mb_.y, mb_.z)); \
      const float4* w_ = (const float4*)(sgw + ((q)*32 + (hh))*40); \
      const float4 W0 = w_[0], W1 = w_[1], W2 = w_[2], W3 = w_[3]; \
      DOT32(a_, W0, W1, W2, W3, HA, HB, HC, HD); dst = a_; }
#define LSTM_U(u, creg) { const int hh_ = s + 16*(u); \
      float ai_, af_, ag_, ao_; \
      GDOTF(0, hh_, ai_) GDOTF(1, hh_, af_) GDOTF(2, hh_, ag_) GDOTF(3, hh_, ao_) \
      const float ig_ = sigm(ai_), fg_ = sigm(af_), gg_ = tanh_f(ag_), og_ = sigm(ao_); \
      creg = fmaf(fg_, creg, ig_*gg_); \
      sh[i*40 + hh_] = (_Float16)(og_ * tanh_f(creg)); }
      LSTM_U(0, c0r) LSTM_U(1, c1r)
#undef LSTM_U
#undef GDOTF
    }

    // ---- P2: a = h @ enc2att_W^T + b; write row-major f16 + transposed f16 ----
    {
      const float4* hp = (const float4*)(sh + i*40);   // new h (same-wave order)
      const float4 GA = hp[0], GB = hp[1], GC = hp[2], GD = hp[3];
#define AOUT(u) { const int k_ = s + 16*(u); \
      float acc_ = se2ab[k_]; \
      const float4* wr_ = (const float4*)(se2a + k_*40); \
      const float4 W0 = wr_[0], W1 = wr_[1], W2 = wr_[2], W3 = wr_[3]; \
      DOT32(acc_, W0, W1, W2, W3, GA, GB, GC, GD); \
      const _Float16 ah_ = (_Float16)acc_; \
      sazf[i*72 + k_] = ah_; saT[k_*72 + i] = ah_; }
      AOUT(0) AOUT(1)
#undef AOUT
    }
    __syncthreads();  // B2: saT visible to all waves (3b reads every node's a)

    // ---- 3a: normalized edge weights -> swf[i][j] f16 (row-local) ----
    {
      const float mi_ = sm[i*20 + t];
      float rs = 0.0f;
#define WCOMP(jj) float wn##jj; { \
      int ib_ = (int)floorf(bm##jj * (1.0f/30.0f)); ib_ = ib_ < 0 ? 0 : (ib_ > 11 ? 11 : ib_); \
      int ih_ = (int)floorf(hm##jj * (1.0f/30.0f)); ih_ = ih_ < 0 ? 0 : (ih_ > 11 ? 11 : ih_); \
      float w_ = fmaxf(sdom[ib_*12 + ih_] - dm##jj, 0.0f) * (mi_ * sm[(s + 16*(jj))*20 + t]); \
      wn##jj = (s + 16*(jj) == i) ? 0.0f : w_; rs += wn##jj; }
      WCOMP(0) WCOMP(1) WCOMP(2) WCOMP(3)
#undef WCOMP
      rs += __shfl_xor(rs, 1); rs += __shfl_xor(rs, 2);
      rs += __shfl_xor(rs, 4); rs += __shfl_xor(rs, 8);
      const float inv_ = __builtin_amdgcn_rcpf(rs + 1e-12f);
      swf[i*72 + s +  0] = (_Float16)(wn0 * inv_);
      swf[i*72 + s + 16] = (_Float16)(wn1 * inv_);
      swf[i*72 + s + 32] = (_Float16)(wn2 * inv_);
      swf[i*72 + s + 48] = (_Float16)(wn3 * inv_);
    }

    // ---- 3b: att[i][m] via fdot2 over j-pairs. Lane (p = s>>3, m8 = s&7)
    // owns m = m8 + 8*mm (stride 8: keeps saT row bank-bases 2-way), j-half
    // 32p..32p+31; halves combined with shfl_xor(8). ----
    {
      const int p  = s >> 3;
      const int m8 = s & 7;
      const float4* wp = (const float4*)(swf + i*72 + 32*p);
      const float4 Wa = wp[0], Wb = wp[1], Wc = wp[2], Wd = wp[3];
      float acc0 = 0.f, acc1 = 0.f, acc2 = 0.f, acc3 = 0.f;
#define ATTM(mm, accv) { \
      const float4* ap = (const float4*)(saT + ((m8) + 8*(mm))*72 + 32*p); \
      const float4 A0 = ap[0], A1 = ap[1], A2 = ap[2], A3 = ap[3]; \
      DOT32(accv, Wa, Wb, Wc, Wd, A0, A1, A2, A3); }
      ATTM(0, acc0) ATTM(1, acc1) ATTM(2, acc2) ATTM(3, acc3)
#undef ATTM
      acc0 += __shfl_xor(acc0, 8); acc1 += __shfl_xor(acc1, 8);
      acc2 += __shfl_xor(acc2, 8); acc3 += __shfl_xor(acc3, 8);
      if (p == 0) {
        sazf[i*72 + 32 + m8]      = (_Float16)acc0;
        sazf[i*72 + 32 + m8 + 8]  = (_Float16)acc1;
        sazf[i*72 + 32 + m8 + 16] = (_Float16)acc2;
        sazf[i*72 + 32 + m8 + 24] = (_Float16)acc3;
      }
    }
    // att written by own node's lanes (same wave) -> P4 needs no barrier

    // ---- P4: z_k = tanh([a|att][i] . spa_W[k] + b), k = s+16u ----
    {
      const float4* rp = (const float4*)(sazf + i*72);  // 64 halves = 8 float4
      const float4 R0 = rp[0], R1 = rp[1], R2 = rp[2], R3 = rp[3];
      const float4 R4_ = rp[4], R5_ = rp[5], R6_ = rp[6], R7_ = rp[7];
#define ZCOMP(u) { const int k_ = s + 16*(u); \
      float acc_ = sspab[k_]; \
      const float4* wr_ = (const float4*)(sspa + k_*72); \
      const float4 W0 = wr_[0], W1 = wr_[1], W2 = wr_[2], W3 = wr_[3]; \
      const float4 W4 = wr_[4], W5 = wr_[5], W6 = wr_[6], W7 = wr_[7]; \
      DOT32(acc_, W0, W1, W2, W3, R0, R1, R2, R3); \
      DOT32(acc_, W4, W5, W6, W7, R4_, R5_, R6_, R7_); \
      sazf[i*72 + k_] = (_Float16)tanh_f(acc_); }   /* reuse a-slot for z: row-local */
      ZCOMP(0) ZCOMP(1)
#undef ZCOMP
    }

    // ---- P5: h = z @ att2enc_W^T + b (row-local, same-wave) ----
    {
      const float4* zp = (const float4*)(sazf + i*72);
      const float4 Z0 = zp[0], Z1 = zp[1], Z2 = zp[2], Z3 = zp[3];
#define HOUT(u) { const int k_ = s + 16*(u); \
      float acc_ = sa2eb[k_]; \
      const float4* wr_ = (const float4*)(sa2e + k_*40); \
      const float4 W0 = wr_[0], W1 = wr_[1], W2 = wr_[2], W3 = wr_[3]; \
      DOT32(acc_, W0, W1, W2, W3, Z0, Z1, Z2, Z3); \
      sh[i*40 + k_] = (_Float16)acc_; }
      HOUT(0) HOUT(1)
#undef HOUT
    }
    __syncthreads();  // Bend: all 3b reads of saT done before next-step P2 rewrites
  }

  // ---- classifier head ----
  if (tid < 64) {
    float acc = sclsb;
    #pragma unroll
    for (int hh = 0; hh < 32; ++hh) acc = fmaf((float)sh[tid*40 + hh], sclsW[hh], acc);
    out[(size_t)b*64 + tid] = sigm(tanh_f(acc));
  }
}

extern "C" void kernel_launch(void* const* d_in, const int* in_sizes, int n_in,
                              void* d_out, int out_size, void* d_ws, size_t ws_size,
                              hipStream_t stream) {
  (void)in_sizes; (void)n_in; (void)d_ws; (void)ws_size; (void)out_size;
  const float* x    = (const float*)d_in[0];
  const float* dmat = (const float*)d_in[1];
  const float* bmat = (const float*)d_in[2];
  const float* hmat = (const float*)d_in[3];
  const float* mask = (const float*)d_in[4];
  const float* embW = (const float*)d_in[5];
  const float* embb = (const float*)d_in[6];
  const float* Wih  = (const float*)d_in[7];
  const float* Whh  = (const float*)d_in[8];
  const float* bih  = (const float*)d_in[9];
  const float* bhh  = (const float*)d_in[10];
  const float* dom  = (const float*)d_in[11];
  const float* e2aW = (const float*)d_in[12];
  const float* e2ab = (const float*)d_in[13];
  const float* spaW = (const float*)d_in[14];
  const float* spab = (const float*)d_in[15];
  const float* a2eW = (const float*)d_in[16];
  const float* a2eb = (const float*)d_in[17];
  const float* clsW = (const float*)d_in[18];
  const float* clsb = (const float*)d_in[19];
  const float* h0   = (const float*)d_in[20];
  const float* c0   = (const float*)d_in[21];
  float* out = (float*)d_out;

  traj_disc<<<dim3(128), dim3(1024), 0, stream>>>(
      x, dmat, bmat, hmat, mask, embW, embb, Wih, Whh, bih, bhh, dom,
      e2aW, e2ab, spaW, spab, a2eW, a2eb, clsW, clsb, h0, c0, out);
}

// Round 7
// 238.383 us; speedup vs baseline: 6.3741x; 1.1534x over previous
//
#include <hip/hip_runtime.h>
#include <math.h>

#define T_STEPS 20

typedef _Float16 half8 __attribute__((ext_vector_type(8)));
typedef _Float16 half4v __attribute__((ext_vector_type(4)));
typedef float f32x4 __attribute__((ext_vector_type(4)));

// fast transcendentals: v_exp + v_rcp (~1e-7 abs err; threshold is 9.7e-3)
__device__ __forceinline__ float sigm(float v) {
  return __builtin_amdgcn_rcpf(1.0f + __expf(-v));
}
__device__ __forceinline__ float tanh_f(float v) {
  return 1.0f - 2.0f * __builtin_amdgcn_rcpf(1.0f + __expf(2.0f * v));
}

// One block per batch (grid=128; R5: per-step cross-block sync is ~60 µs/step
// — unaffordable). 1024 threads = 16 waves. R6 was LDS-issue-pipe-bound
// (~112 ds_read_b128/lane-step). This version runs every GEMM on the MFMA
// pipe (mfma_f32_16x16x32_f16): fragments are dense (1 b128 = 8 halves), so
// DS instruction count drops ~3x and the dot work leaves VALU entirely.
// Layouts (verified m89/m120): A[m=lane&15][k=quad*8+j] from row-major [m][k];
// B[k=quad*8+j][n=lane&15] from row-major [n][k]; D row=(lane>>4)*4+reg,
// col=lane&15.
// Algebraic folding (exact): P = H@ESa, Q = H@ESt with ESa/ESt = e2aW^T @
// spaW halves precomputed; Z = tanh(P + Wn@Q + bz), bz absorbs spab and the
// e2ab paths (direct + attention, using sum_j wn = 1 up to 1e-12).
// ZERO per-thread arrays (R1/R2: arrays = scratch = HBM).
__global__ __launch_bounds__(1024)
void traj_disc(const float* __restrict__ x, const float* __restrict__ dmat,
               const float* __restrict__ bmat, const float* __restrict__ hmat,
               const float* __restrict__ maskp,
               const float* __restrict__ embW, const float* __restrict__ embb,
               const float* __restrict__ Wih, const float* __restrict__ Whh,
               const float* __restrict__ bih, const float* __restrict__ bhh,
               const float* __restrict__ dom,
               const float* __restrict__ e2aW, const float* __restrict__ e2ab,
               const float* __restrict__ spaW, const float* __restrict__ spab,
               const float* __restrict__ a2eW, const float* __restrict__ a2eb,
               const float* __restrict__ clsW, const float* __restrict__ clsb,
               const float* __restrict__ h0p, const float* __restrict__ c0p,
               float* __restrict__ out)
{
  // f16 pitches 40/72 halves (80/144 B: 16B-aligned rows, 2-way banks max).
  // f32 gate buffer pitch 68 (272 B: 16B-aligned, 2-way banks).
  __shared__ __align__(16) _Float16 sgw[128*40];   // Whh[gate][k]
  __shared__ __align__(16) float4   sgmb[128];     // (M0, M1, bias', 0) f32
  __shared__ __align__(16) _Float16 sESaT[32*40];  // ESa^T[zk][h]
  __shared__ __align__(16) _Float16 sEStT[32*40];  // ESt^T[zk][h]
  __shared__ __align__(16) _Float16 sa2e[32*40];   // a2eW[hout][zk]
  __shared__ float bz[32];                          // folded z bias
  __shared__ float sa2eb[32];
  __shared__ float sdom[144];
  __shared__ float sm[1280];                        // mask[b] as [n][t]
  __shared__ float sclsW[32];
  __shared__ float sclsb;
  __shared__ __align__(16) _Float16 sH[64*40];     // h rows f16
  __shared__ __align__(16) _Float16 sw[64*72];     // normalized w[i][j] f16
  __shared__ __align__(16) _Float16 sz_[64*40];    // z rows f16
  __shared__ __align__(16) _Float16 sQT[32*72];    // Q^T[zk][node] f16
  __shared__ __align__(16) float sgates[128*68];   // gates[gate][node] f32; rows 0..31 reused as P[zk][node]

  const int tid = threadIdx.x;
  const int b = blockIdx.x;
  const int i = tid >> 4;     // node 0..63 (nonlin/3a decomposition)
  const int s = tid & 15;     // sub-lane 0..15
  const int w = tid >> 6;     // wave 0..15 (MFMA decomposition)
  const int l = tid & 63;
  const int quad = l >> 4;
  const int n16 = l & 15;

  // ---- one-time staging ----
  for (int idx = tid; idx < 4096; idx += 1024) sgw[(idx >> 5)*40 + (idx & 31)] = (_Float16)Whh[idx];
  if (tid < 128) {
    float m0 = 0.f, m1 = 0.f, bb = bih[tid] + bhh[tid];
    #pragma unroll
    for (int e = 0; e < 16; ++e) {
      float wv_ = Wih[tid*16 + e];
      m0 = fmaf(wv_, embW[2*e],   m0);
      m1 = fmaf(wv_, embW[2*e+1], m1);
      bb = fmaf(wv_, embb[e],     bb);
    }
    sgmb[tid] = make_float4(m0, m1, bb, 0.f);
  }
  {  // ESa^T / ESt^T: entry (zk = tid>>5, h = tid&31), f32 accumulate -> f16
    const int zk = tid >> 5, hc = tid & 31;
    float sa_ = 0.f, st_ = 0.f;
    #pragma unroll
    for (int a = 0; a < 32; ++a) {
      const float ev = e2aW[a*32 + hc];
      sa_ = fmaf(spaW[zk*64 + a],      ev, sa_);
      st_ = fmaf(spaW[zk*64 + 32 + a], ev, st_);
    }
    sESaT[zk*40 + hc] = (_Float16)sa_;
    sEStT[zk*40 + hc] = (_Float16)st_;
  }
  for (int idx = tid; idx < 1024; idx += 1024) sa2e[(idx >> 5)*40 + (idx & 31)] = (_Float16)a2eW[idx];
  if (tid < 32) {
    float acc = spab[tid];
    #pragma unroll
    for (int a = 0; a < 32; ++a)
      acc = fmaf(e2ab[a], spaW[tid*64 + a] + spaW[tid*64 + 32 + a], acc);
    bz[tid] = acc;
    sa2eb[tid] = a2eb[tid];
    sclsW[tid] = clsW[tid];
  }
  if (tid < 144) sdom[tid] = dom[tid];
  if (tid == 0) sclsb = clsb[0];
  for (int idx = tid; idx < 1280; idx += 1024) sm[idx] = maskp[(size_t)b*1280 + idx];
  for (int idx = tid; idx < 2048; idx += 1024) sH[(idx >> 5)*40 + (idx & 31)] = (_Float16)h0p[(size_t)b*2048 + idx];
  float c0r = c0p[(size_t)b*2048 + i*32 + s];       // cell f32, hh = s
  float c1r = c0p[(size_t)b*2048 + i*32 + s + 16];  // cell f32, hh = s+16
  __syncthreads();

  const size_t nb = (size_t)b*64 + i;

  #pragma unroll 1
  for (int t = 0; t < T_STEPS; ++t) {
    // edge loads for 3a: 12 NAMED scalars (never an array)
    const size_t ebase = (nb*20 + t)*64;
#define EDGELD(jj) const float dm##jj = dmat[ebase + s + 16*(jj)]; \
                   const float bm##jj = bmat[ebase + s + 16*(jj)]; \
                   const float hm##jj = hmat[ebase + s + 16*(jj)];
    EDGELD(0) EDGELD(1) EDGELD(2) EDGELD(3)
#undef EDGELD

    // ---- op1: Gates[node][gate] = H @ Whh^T + x-part (C-init). 32 tiles,
    // wave w does (r1 = w>>2, c = 2(w&3), 2(w&3)+1), A shared across c. ----
    {
      const int r1 = w >> 2, cp = (w & 3) << 1;
      const half8 Af = *(const half8*)(sH + (16*r1 + n16)*40 + quad*8);
      const float* xb = x + (((size_t)b*64 + 16*r1 + 4*quad)*20 + t)*2;
      const float2 xA = *(const float2*)(xb +   0);   // node +0 (stride 40 f)
      const float2 xB = *(const float2*)(xb +  40);
      const float2 xC = *(const float2*)(xb +  80);
      const float2 xD = *(const float2*)(xb + 120);
#define OP1C(c) { \
      const half8 Bf = *(const half8*)(sgw + (16*(c) + n16)*40 + quad*8); \
      const float4 mb = sgmb[16*(c) + n16]; \
      f32x4 Cv; \
      Cv[0] = fmaf(xA.x, mb.x, fmaf(xA.y, mb.y, mb.z)); \
      Cv[1] = fmaf(xB.x, mb.x, fmaf(xB.y, mb.y, mb.z)); \
      Cv[2] = fmaf(xC.x, mb.x, fmaf(xC.y, mb.y, mb.z)); \
      Cv[3] = fmaf(xD.x, mb.x, fmaf(xD.y, mb.y, mb.z)); \
      Cv = __builtin_amdgcn_mfma_f32_16x16x32_f16(Af, Bf, Cv, 0, 0, 0); \
      *(f32x4*)(sgates + (16*(c) + n16)*68 + 16*r1 + 4*quad) = Cv; }
      OP1C(cp) OP1C(cp + 1)
#undef OP1C
    }
    __syncthreads();  // B1: gates visible

    // ---- nonlin: LSTM cell per (i, hh = s + 16u); c stays in this lane ----
    {
#define GR(q, u) sgates[((q)*32 + s + 16*(u))*68 + i]
      const float ai0 = GR(0,0), af0 = GR(1,0), ag0 = GR(2,0), ao0 = GR(3,0);
      const float ai1 = GR(0,1), af1 = GR(1,1), ag1 = GR(2,1), ao1 = GR(3,1);
#undef GR
      c0r = fmaf(sigm(af0), c0r, sigm(ai0)*tanh_f(ag0));
      sH[i*40 + s]      = (_Float16)(sigm(ao0)*tanh_f(c0r));
      c1r = fmaf(sigm(af1), c1r, sigm(ai1)*tanh_f(ag1));
      sH[i*40 + s + 16] = (_Float16)(sigm(ao1)*tanh_f(c1r));
    }
    // ---- 3a: normalized edge weights -> sw[i][j] f16 (row-local) ----
    {
      const float mi_ = sm[i*20 + t];
      float rs = 0.0f;
#define WCOMP(jj) float wn##jj; { \
      int ib_ = (int)floorf(bm##jj * (1.0f/30.0f)); ib_ = ib_ < 0 ? 0 : (ib_ > 11 ? 11 : ib_); \
      int ih_ = (int)floorf(hm##jj * (1.0f/30.0f)); ih_ = ih_ < 0 ? 0 : (ih_ > 11 ? 11 : ih_); \
      float w_ = fmaxf(sdom[ib_*12 + ih_] - dm##jj, 0.0f) * (mi_ * sm[(s + 16*(jj))*20 + t]); \
      wn##jj = (s + 16*(jj) == i) ? 0.0f : w_; rs += wn##jj; }
      WCOMP(0) WCOMP(1) WCOMP(2) WCOMP(3)
#undef WCOMP
      rs += __shfl_xor(rs, 1); rs += __shfl_xor(rs, 2);
      rs += __shfl_xor(rs, 4); rs += __shfl_xor(rs, 8);
      const float inv_ = __builtin_amdgcn_rcpf(rs + 1e-12f);
      sw[i*72 + s +  0] = (_Float16)(wn0 * inv_);
      sw[i*72 + s + 16] = (_Float16)(wn1 * inv_);
      sw[i*72 + s + 32] = (_Float16)(wn2 * inv_);
      sw[i*72 + s + 48] = (_Float16)(wn3 * inv_);
    }
    __syncthreads();  // B2: h + w visible

    // ---- op2a/op2b concurrent: P = H@ESa (waves 0-7, f32 -> sgates rows
    // 0..31 as P[zk][node]); Q = H@ESt (waves 8-15, f16 -> sQT[zk][node]) ----
    if (w < 8) {
      const int r = w >> 1, c = w & 1;
      const half8 Af = *(const half8*)(sH    + (16*r + n16)*40 + quad*8);
      const half8 Bf = *(const half8*)(sESaT + (16*c + n16)*40 + quad*8);
      f32x4 Cv = {0.f, 0.f, 0.f, 0.f};
      Cv = __builtin_amdgcn_mfma_f32_16x16x32_f16(Af, Bf, Cv, 0, 0, 0);
      *(f32x4*)(sgates + (16*c + n16)*68 + 16*r + 4*quad) = Cv;
    } else {
      const int w8 = w - 8, r = w8 >> 1, c = w8 & 1;
      const half8 Af = *(const half8*)(sH    + (16*r + n16)*40 + quad*8);
      const half8 Bf = *(const half8*)(sEStT + (16*c + n16)*40 + quad*8);
      f32x4 Cv = {0.f, 0.f, 0.f, 0.f};
      Cv = __builtin_amdgcn_mfma_f32_16x16x32_f16(Af, Bf, Cv, 0, 0, 0);
      half4v hq;
      hq[0] = (_Float16)Cv[0]; hq[1] = (_Float16)Cv[1];
      hq[2] = (_Float16)Cv[2]; hq[3] = (_Float16)Cv[3];
      *(half4v*)(sQT + (16*c + n16)*72 + 16*r + 4*quad) = hq;
    }
    __syncthreads();  // B3: P + Q^T visible

    // ---- op3: Z = tanh(P + Wn@Q + bz) (waves 8-15; K=64 = 2 chunks) ----
    if (w >= 8) {
      const int w8 = w - 8, r = w8 >> 1, c = w8 & 1;
      const half8 A0 = *(const half8*)(sw  + (16*r + n16)*72 + quad*8);
      const half8 A1 = *(const half8*)(sw  + (16*r + n16)*72 + 32 + quad*8);
      const half8 B0 = *(const half8*)(sQT + (16*c + n16)*72 + quad*8);
      const half8 B1 = *(const half8*)(sQT + (16*c + n16)*72 + 32 + quad*8);
      const f32x4 Pv = *(const f32x4*)(sgates + (16*c + n16)*68 + 16*r + 4*quad);
      const float bzv = bz[16*c + n16];
      f32x4 Cv;
      Cv[0] = Pv[0] + bzv; Cv[1] = Pv[1] + bzv;
      Cv[2] = Pv[2] + bzv; Cv[3] = Pv[3] + bzv;
      Cv = __builtin_amdgcn_mfma_f32_16x16x32_f16(A0, B0, Cv, 0, 0, 0);
      Cv = __builtin_amdgcn_mfma_f32_16x16x32_f16(A1, B1, Cv, 0, 0, 0);
      const int nd = 16*r + 4*quad;
      sz_[(nd+0)*40 + 16*c + n16] = (_Float16)tanh_f(Cv[0]);
      sz_[(nd+1)*40 + 16*c + n16] = (_Float16)tanh_f(Cv[1]);
      sz_[(nd+2)*40 + 16*c + n16] = (_Float16)tanh_f(Cv[2]);
      sz_[(nd+3)*40 + 16*c + n16] = (_Float16)tanh_f(Cv[3]);
    }
    __syncthreads();  // B4: z visible

    // ---- op5: Hn = Z @ a2eW^T + b (waves 0-7) ----
    if (w < 8) {
      const int r = w >> 1, c = w & 1;
      const half8 Af = *(const half8*)(sz_  + (16*r + n16)*40 + quad*8);
      const half8 Bf = *(const half8*)(sa2e + (16*c + n16)*40 + quad*8);
      const float bv = sa2eb[16*c + n16];
      f32x4 Cv = {bv, bv, bv, bv};
      Cv = __builtin_amdgcn_mfma_f32_16x16x32_f16(Af, Bf, Cv, 0, 0, 0);
      const int nd = 16*r + 4*quad;
      sH[(nd+0)*40 + 16*c + n16] = (_Float16)Cv[0];
      sH[(nd+1)*40 + 16*c + n16] = (_Float16)Cv[1];
      sH[(nd+2)*40 + 16*c + n16] = (_Float16)Cv[2];
      sH[(nd+3)*40 + 16*c + n16] = (_Float16)Cv[3];
    }
    __syncthreads();  // Bend: sH final for this step
  }

  // ---- classifier head ----
  if (tid < 64) {
    float acc = sclsb;
    #pragma unroll
    for (int hh = 0; hh < 32; ++hh) acc = fmaf((float)sH[tid*40 + hh], sclsW[hh], acc);
    out[(size_t)b*64 + tid] = sigm(tanh_f(acc));
  }
}

extern "C" void kernel_launch(void* const* d_in, const int* in_sizes, int n_in,
                              void* d_out, int out_size, void* d_ws, size_t ws_size,
                              hipStream_t stream) {
  (void)in_sizes; (void)n_in; (void)d_ws; (void)ws_size; (void)out_size;
  const float* x    = (const float*)d_in[0];
  const float* dmat = (const float*)d_in[1];
  const float* bmat = (const float*)d_in[2];
  const float* hmat = (const float*)d_in[3];
  const float* mask = (const float*)d_in[4];
  const float* embW = (const float*)d_in[5];
  const float* embb = (const float*)d_in[6];
  const float* Wih  = (const float*)d_in[7];
  const float* Whh  = (const float*)d_in[8];
  const float* bih  = (const float*)d_in[9];
  const float* bhh  = (const float*)d_in[10];
  const float* dom  = (const float*)d_in[11];
  const float* e2aW = (const float*)d_in[12];
  const float* e2ab = (const float*)d_in[13];
  const float* spaW = (const float*)d_in[14];
  const float* spab = (const float*)d_in[15];
  const float* a2eW = (const float*)d_in[16];
  const float* a2eb = (const float*)d_in[17];
  const float* clsW = (const float*)d_in[18];
  const float* clsb = (const float*)d_in[19];
  const float* h0   = (const float*)d_in[20];
  const float* c0   = (const float*)d_in[21];
  float* out = (float*)d_out;

  traj_disc<<<dim3(128), dim3(1024), 0, stream>>>(
      x, dmat, bmat, hmat, mask, embW, embb, Wih, Whh, bih, bhh, dom,
      e2aW, e2ab, spaW, spab, a2eW, a2eb, clsW, clsb, h0, c0, out);
}

// Round 8
// 225.046 us; speedup vs baseline: 6.7519x; 1.0593x over previous
//
#include <hip/hip_runtime.h>
#include <math.h>

#define T_STEPS 20

typedef _Float16 half8 __attribute__((ext_vector_type(8)));
typedef _Float16 half4v __attribute__((ext_vector_type(4)));
typedef float f32x4 __attribute__((ext_vector_type(4)));

// fast transcendentals: v_exp + v_rcp (~1e-7 abs err; threshold is 9.7e-3)
__device__ __forceinline__ float sigm(float v) {
  return __builtin_amdgcn_rcpf(1.0f + __expf(-v));
}
__device__ __forceinline__ float tanh_f(float v) {
  return 1.0f - 2.0f * __builtin_amdgcn_rcpf(1.0f + __expf(2.0f * v));
}

// One block per batch (grid=128; R5: cross-block per-step sync ~60 µs/step —
// unaffordable). 1024 threads = 16 waves. R7 was phase/barrier-latency-bound
// (all pipes <30% on active CUs). This version:
//  - carries Z as the recurrent state: h_carry = Z@a2e^T+b only feeds the
//    next gates, so gates = Z@(Whh@a2eW)^T + folded-bias (exact algebra);
//    op5 and one barrier are gone. 4 barriers/step.
//  - op2-P accumulators stay in REGISTERS across B3 into op3 (same-wave tile
//    assignment) — no P LDS round-trip.
//  - x/edge HBM loads for t+1 issue in step t's tail (~1 step of latency
//    cover). ZERO per-thread arrays (R1/R2: arrays = scratch = HBM).
// MFMA layouts (verified m89 + R7): A[m=lane&15][k=quad*8+j] from row-major
// [m][k]; B[k][n=lane&15] from row-major [n][k]; D row=4*quad+reg, col=lane&15.
__global__ __launch_bounds__(1024)
void traj_disc(const float* __restrict__ x, const float* __restrict__ dmat,
               const float* __restrict__ bmat, const float* __restrict__ hmat,
               const float* __restrict__ maskp,
               const float* __restrict__ embW, const float* __restrict__ embb,
               const float* __restrict__ Wih, const float* __restrict__ Whh,
               const float* __restrict__ bih, const float* __restrict__ bhh,
               const float* __restrict__ dom,
               const float* __restrict__ e2aW, const float* __restrict__ e2ab,
               const float* __restrict__ spaW, const float* __restrict__ spab,
               const float* __restrict__ a2eW, const float* __restrict__ a2eb,
               const float* __restrict__ clsW, const float* __restrict__ clsb,
               const float* __restrict__ h0p, const float* __restrict__ c0p,
               float* __restrict__ out)
{
  // f16 pitches 40/72 halves (80/144 B: 16B-aligned, <=2-way banks).
  __shared__ __align__(16) _Float16 sgw[128*40];   // Whh[g][h]        (t=0 path)
  __shared__ __align__(16) _Float16 sgwc[128*40];  // (Whh@a2eW)[g][k] (t>0 path)
  __shared__ __align__(16) float4   sgmb[128];     // (M0, M1, b_t0, b_tn)
  __shared__ __align__(16) _Float16 sESaT[32*40];  // (e2aW^T@spaW_a)^T[zk][h]
  __shared__ __align__(16) _Float16 sEStT[32*40];  // (e2aW^T@spaW_t)^T[zk][h]
  __shared__ float bz[32];                          // folded z bias
  __shared__ float sdom[144];
  __shared__ float sm[1280];                        // mask[b] as [n][t]
  __shared__ float sclsc[32];                       // clsW@a2eW fold
  __shared__ float sclsb2[1];
  __shared__ __align__(16) _Float16 sH[64*40];     // h_lstm rows f16 (+h0 at t=0)
  __shared__ __align__(16) _Float16 sw[64*72];     // normalized w[i][j] f16
  __shared__ __align__(16) _Float16 sz_[64*40];    // Z rows f16 (recurrent state)
  __shared__ __align__(16) _Float16 sQT[32*72];    // Q^T[zk][node] f16
  __shared__ __align__(16) float sgates[128*68];   // gates[gate][node] f32

  const int tid = threadIdx.x;
  const int b = blockIdx.x;
  const int i = tid >> 4;     // node 0..63 (nonlin/3a decomposition)
  const int s = tid & 15;     // sub-lane 0..15
  const int w = tid >> 6;     // wave 0..15 (MFMA decomposition)
  const int l = tid & 63;
  const int quad = l >> 4;
  const int n16 = l & 15;

  // ---- one-time staging ----
  for (int idx = tid; idx < 4096; idx += 1024) sgw[(idx >> 5)*40 + (idx & 31)] = (_Float16)Whh[idx];
  {  // Wcomb[g][k] = sum_h Whh[g][h] * a2eW[h][k]; 8 threads per g, 4 k each
    const int g = tid >> 3, kb = (tid & 7) << 2;
    float a0 = 0.f, a1 = 0.f, a2 = 0.f, a3 = 0.f;
    #pragma unroll
    for (int h = 0; h < 32; ++h) {
      const float wv = Whh[g*32 + h];
      a0 = fmaf(wv, a2eW[h*32 + kb + 0], a0);
      a1 = fmaf(wv, a2eW[h*32 + kb + 1], a1);
      a2 = fmaf(wv, a2eW[h*32 + kb + 2], a2);
      a3 = fmaf(wv, a2eW[h*32 + kb + 3], a3);
    }
    sgwc[g*40 + kb + 0] = (_Float16)a0; sgwc[g*40 + kb + 1] = (_Float16)a1;
    sgwc[g*40 + kb + 2] = (_Float16)a2; sgwc[g*40 + kb + 3] = (_Float16)a3;
  }
  if (tid < 128) {  // x-projection fold + both bias variants
    float m0 = 0.f, m1 = 0.f, b0 = bih[tid] + bhh[tid];
    #pragma unroll
    for (int e = 0; e < 16; ++e) {
      float wv_ = Wih[tid*16 + e];
      m0 = fmaf(wv_, embW[2*e],   m0);
      m1 = fmaf(wv_, embW[2*e+1], m1);
      b0 = fmaf(wv_, embb[e],     b0);
    }
    float bn = b0;
    #pragma unroll
    for (int h = 0; h < 32; ++h) bn = fmaf(Whh[tid*32 + h], a2eb[h], bn);
    sgmb[tid] = make_float4(m0, m1, b0, bn);
  }
  {  // ESa^T / ESt^T: entry (zk = tid>>5, h = tid&31)
    const int zk = tid >> 5, hc = tid & 31;
    float sa_ = 0.f, st_ = 0.f;
    #pragma unroll
    for (int a = 0; a < 32; ++a) {
      const float ev = e2aW[a*32 + hc];
      sa_ = fmaf(spaW[zk*64 + a],      ev, sa_);
      st_ = fmaf(spaW[zk*64 + 32 + a], ev, st_);
    }
    sESaT[zk*40 + hc] = (_Float16)sa_;
    sEStT[zk*40 + hc] = (_Float16)st_;
  }
  if (tid < 32) {  // bz fold + classifier fold
    float acc = spab[tid];
    #pragma unroll
    for (int a = 0; a < 32; ++a)
      acc = fmaf(e2ab[a], spaW[tid*64 + a] + spaW[tid*64 + 32 + a], acc);
    bz[tid] = acc;
    float cc = 0.f;
    #pragma unroll
    for (int h = 0; h < 32; ++h) cc = fmaf(clsW[h], a2eW[h*32 + tid], cc);
    sclsc[tid] = cc;
  }
  if (tid == 0) {
    float cb = clsb[0];
    #pragma unroll
    for (int h = 0; h < 32; ++h) cb = fmaf(clsW[h], a2eb[h], cb);
    sclsb2[0] = cb;
  }
  if (tid < 144) sdom[tid] = dom[tid];
  for (int idx = tid; idx < 1280; idx += 1024) sm[idx] = maskp[(size_t)b*1280 + idx];
  for (int idx = tid; idx < 2048; idx += 1024) sH[(idx >> 5)*40 + (idx & 31)] = (_Float16)h0p[(size_t)b*2048 + idx];
  float c0r = c0p[(size_t)b*2048 + i*32 + s];       // cell f32, hh = s
  float c1r = c0p[(size_t)b*2048 + i*32 + s + 16];  // cell f32, hh = s+16
  __syncthreads();

  const size_t nb = (size_t)b*64 + i;

  // ---- prefetched step inputs (NAMED scalars, refreshed in step tail) ----
  const float* xpre = x + (size_t)(b*64 + ((w >> 2) << 4) + (quad << 2)) * 40;
  float2 xA = *(const float2*)(xpre +   0);
  float2 xB = *(const float2*)(xpre +  40);
  float2 xC = *(const float2*)(xpre +  80);
  float2 xD = *(const float2*)(xpre + 120);
  size_t eb_ = nb*1280;   // (nb*20 + 0)*64
  float dm0 = dmat[eb_ + s],      bm0 = bmat[eb_ + s],      hm0 = hmat[eb_ + s];
  float dm1 = dmat[eb_ + s + 16], bm1 = bmat[eb_ + s + 16], hm1 = hmat[eb_ + s + 16];
  float dm2 = dmat[eb_ + s + 32], bm2 = bmat[eb_ + s + 32], hm2 = hmat[eb_ + s + 32];
  float dm3 = dmat[eb_ + s + 48], bm3 = bmat[eb_ + s + 48], hm3 = hmat[eb_ + s + 48];

  #pragma unroll 1
  for (int t = 0; t < T_STEPS; ++t) {
    // ---- op1: Gates[node][g] = State @ W^T + x-part. 32 tiles, 2/wave.
    // t=0: State=h0 (sH), W=Whh; t>0: State=Z (sz_), W=Wcomb. Wave-uniform. ----
    {
      const int r1 = w >> 2, cp = (w & 3) << 1;
      const _Float16* Abase = (t == 0) ? sH : sz_;
      const _Float16* Bbase = (t == 0) ? sgw : sgwc;
      const half8 Af = *(const half8*)(Abase + (16*r1 + n16)*40 + quad*8);
#define OP1C(c) { \
      const half8 Bf = *(const half8*)(Bbase + (16*(c) + n16)*40 + quad*8); \
      const float4 mb = sgmb[16*(c) + n16]; \
      const float bb = (t == 0) ? mb.z : mb.w; \
      f32x4 Cv; \
      Cv[0] = fmaf(xA.x, mb.x, fmaf(xA.y, mb.y, bb)); \
      Cv[1] = fmaf(xB.x, mb.x, fmaf(xB.y, mb.y, bb)); \
      Cv[2] = fmaf(xC.x, mb.x, fmaf(xC.y, mb.y, bb)); \
      Cv[3] = fmaf(xD.x, mb.x, fmaf(xD.y, mb.y, bb)); \
      Cv = __builtin_amdgcn_mfma_f32_16x16x32_f16(Af, Bf, Cv, 0, 0, 0); \
      *(f32x4*)(sgates + (16*(c) + n16)*68 + 16*r1 + 4*quad) = Cv; }
      OP1C(cp) OP1C(cp + 1)
#undef OP1C
    }
    __syncthreads();  // B1: gates visible

    // ---- nonlin: LSTM cell per (i, hh = s + 16u); c stays in this lane ----
    {
#define GR(q, u) sgates[((q)*32 + s + 16*(u))*68 + i]
      const float ai0 = GR(0,0), af0 = GR(1,0), ag0 = GR(2,0), ao0 = GR(3,0);
      const float ai1 = GR(0,1), af1 = GR(1,1), ag1 = GR(2,1), ao1 = GR(3,1);
#undef GR
      c0r = fmaf(sigm(af0), c0r, sigm(ai0)*tanh_f(ag0));
      sH[i*40 + s]      = (_Float16)(sigm(ao0)*tanh_f(c0r));
      c1r = fmaf(sigm(af1), c1r, sigm(ai1)*tanh_f(ag1));
      sH[i*40 + s + 16] = (_Float16)(sigm(ao1)*tanh_f(c1r));
    }
    // ---- 3a: normalized edge weights -> sw[i][j] f16 (row-local) ----
    {
      const float mi_ = sm[i*20 + t];
      float rs = 0.0f;
#define WCOMP(jj) float wn##jj; { \
      int ib_ = (int)floorf(bm##jj * (1.0f/30.0f)); ib_ = ib_ < 0 ? 0 : (ib_ > 11 ? 11 : ib_); \
      int ih_ = (int)floorf(hm##jj * (1.0f/30.0f)); ih_ = ih_ < 0 ? 0 : (ih_ > 11 ? 11 : ih_); \
      float w_ = fmaxf(sdom[ib_*12 + ih_] - dm##jj, 0.0f) * (mi_ * sm[(s + 16*(jj))*20 + t]); \
      wn##jj = (s + 16*(jj) == i) ? 0.0f : w_; rs += wn##jj; }
      WCOMP(0) WCOMP(1) WCOMP(2) WCOMP(3)
#undef WCOMP
      rs += __shfl_xor(rs, 1); rs += __shfl_xor(rs, 2);
      rs += __shfl_xor(rs, 4); rs += __shfl_xor(rs, 8);
      const float inv_ = __builtin_amdgcn_rcpf(rs + 1e-12f);
      sw[i*72 + s +  0] = (_Float16)(wn0 * inv_);
      sw[i*72 + s + 16] = (_Float16)(wn1 * inv_);
      sw[i*72 + s + 32] = (_Float16)(wn2 * inv_);
      sw[i*72 + s + 48] = (_Float16)(wn3 * inv_);
    }
    // ---- prefetch t+1 inputs (edges + x): ~a full step of latency cover ----
    {
      const int tn = (t < T_STEPS - 1) ? t + 1 : t;
      const size_t ebn = (nb*20 + tn)*64;
      dm0 = dmat[ebn + s];      bm0 = bmat[ebn + s];      hm0 = hmat[ebn + s];
      dm1 = dmat[ebn + s + 16]; bm1 = bmat[ebn + s + 16]; hm1 = hmat[ebn + s + 16];
      dm2 = dmat[ebn + s + 32]; bm2 = bmat[ebn + s + 32]; hm2 = hmat[ebn + s + 32];
      dm3 = dmat[ebn + s + 48]; bm3 = bmat[ebn + s + 48]; hm3 = hmat[ebn + s + 48];
      const int tn2 = tn << 1;
      xA = *(const float2*)(xpre + tn2);
      xB = *(const float2*)(xpre + tn2 +  40);
      xC = *(const float2*)(xpre + tn2 +  80);
      xD = *(const float2*)(xpre + tn2 + 120);
    }
    __syncthreads();  // B2: h_lstm + w visible

    // ---- op2: waves 0-7 P = H@ESa + bz (REGISTERS); waves 8-15 Q -> sQT ----
    f32x4 Pv = {0.f, 0.f, 0.f, 0.f};
    if (w < 8) {
      const int r = w >> 1, c = w & 1;
      const half8 Af = *(const half8*)(sH    + (16*r + n16)*40 + quad*8);
      const half8 Bf = *(const half8*)(sESaT + (16*c + n16)*40 + quad*8);
      const float bzv = bz[16*c + n16];
      Pv[0] = bzv; Pv[1] = bzv; Pv[2] = bzv; Pv[3] = bzv;
      Pv = __builtin_amdgcn_mfma_f32_16x16x32_f16(Af, Bf, Pv, 0, 0, 0);
    } else {
      const int w8 = w - 8, r = w8 >> 1, c = w8 & 1;
      const half8 Af = *(const half8*)(sH    + (16*r + n16)*40 + quad*8);
      const half8 Bf = *(const half8*)(sEStT + (16*c + n16)*40 + quad*8);
      f32x4 Cv = {0.f, 0.f, 0.f, 0.f};
      Cv = __builtin_amdgcn_mfma_f32_16x16x32_f16(Af, Bf, Cv, 0, 0, 0);
      half4v hq;
      hq[0] = (_Float16)Cv[0]; hq[1] = (_Float16)Cv[1];
      hq[2] = (_Float16)Cv[2]; hq[3] = (_Float16)Cv[3];
      *(half4v*)(sQT + (16*c + n16)*72 + 16*r + 4*quad) = hq;
    }
    __syncthreads();  // B3: Q^T visible (P rides in registers)

    // ---- op3: Z = tanh(Pv + Wn@Q) (waves 0-7, same tile as their P) ----
    if (w < 8) {
      const int r = w >> 1, c = w & 1;
      const half8 A0 = *(const half8*)(sw  + (16*r + n16)*72 + quad*8);
      const half8 A1 = *(const half8*)(sw  + (16*r + n16)*72 + 32 + quad*8);
      const half8 B0 = *(const half8*)(sQT + (16*c + n16)*72 + quad*8);
      const half8 B1 = *(const half8*)(sQT + (16*c + n16)*72 + 32 + quad*8);
      Pv = __builtin_amdgcn_mfma_f32_16x16x32_f16(A0, B0, Pv, 0, 0, 0);
      Pv = __builtin_amdgcn_mfma_f32_16x16x32_f16(A1, B1, Pv, 0, 0, 0);
      const int nd = 16*r + 4*quad;
      sz_[(nd+0)*40 + 16*c + n16] = (_Float16)tanh_f(Pv[0]);
      sz_[(nd+1)*40 + 16*c + n16] = (_Float16)tanh_f(Pv[1]);
      sz_[(nd+2)*40 + 16*c + n16] = (_Float16)tanh_f(Pv[2]);
      sz_[(nd+3)*40 + 16*c + n16] = (_Float16)tanh_f(Pv[3]);
    }
    __syncthreads();  // Bend: Z final for this step (op1(t+1) reads it)
  }

  // ---- classifier head (folded through a2e): out = sigm(tanh(z.clsc + b)) ----
  if (tid < 64) {
    float acc = sclsb2[0];
    #pragma unroll
    for (int k = 0; k < 32; ++k) acc = fmaf((float)sz_[tid*40 + k], sclsc[k], acc);
    out[(size_t)b*64 + tid] = sigm(tanh_f(acc));
  }
}

extern "C" void kernel_launch(void* const* d_in, const int* in_sizes, int n_in,
                              void* d_out, int out_size, void* d_ws, size_t ws_size,
                              hipStream_t stream) {
  (void)in_sizes; (void)n_in; (void)d_ws; (void)ws_size; (void)out_size;
  const float* x    = (const float*)d_in[0];
  const float* dmat = (const float*)d_in[1];
  const float* bmat = (const float*)d_in[2];
  const float* hmat = (const float*)d_in[3];
  const float* mask = (const float*)d_in[4];
  const float* embW = (const float*)d_in[5];
  const float* embb = (const float*)d_in[6];
  const float* Wih  = (const float*)d_in[7];
  const float* Whh  = (const float*)d_in[8];
  const float* bih  = (const float*)d_in[9];
  const float* bhh  = (const float*)d_in[10];
  const float* dom  = (const float*)d_in[11];
  const float* e2aW = (const float*)d_in[12];
  const float* e2ab = (const float*)d_in[13];
  const float* spaW = (const float*)d_in[14];
  const float* spab = (const float*)d_in[15];
  const float* a2eW = (const float*)d_in[16];
  const float* a2eb = (const float*)d_in[17];
  const float* clsW = (const float*)d_in[18];
  const float* clsb = (const float*)d_in[19];
  const float* h0   = (const float*)d_in[20];
  const float* c0   = (const float*)d_in[21];
  float* out = (float*)d_out;

  traj_disc<<<dim3(128), dim3(1024), 0, stream>>>(
      x, dmat, bmat, hmat, mask, embW, embb, Wih, Whh, bih, bhh, dom,
      e2aW, e2ab, spaW, spab, a2eW, a2eb, clsW, clsb, h0, c0, out);
}